// Round 4
// baseline (547.191 us; speedup 1.0000x reference)
//
#include <hip/hip_runtime.h>
#include <math.h>

#define BN 8
#define SN 2048
#define DN 512
#define UN 512
#define MN (BN*SN)   // 16384

typedef _Float16 f16;
typedef _Float16 f16x8 __attribute__((ext_vector_type(8)));
typedef _Float16 f16x4 __attribute__((ext_vector_type(4)));
typedef float    f32x4 __attribute__((ext_vector_type(4)));

#define SCALE 0.044194173824159216f   // 1/sqrt(512), folded into W_q at convert
#define LOG2E 1.4426950408889634f
#define DEFER_THR 8.0f

__device__ __forceinline__ void gload_lds16(const f16* g, f16* l) {
  __builtin_amdgcn_global_load_lds(
      (const __attribute__((address_space(1))) unsigned int*)g,
      (__attribute__((address_space(3))) unsigned int*)l, 16, 0, 0);
}

// ---------------- fp32 -> fp16 convert of x ----------------
__global__ __launch_bounds__(256) void cvt_x_kernel(const float* __restrict__ x,
                                                    f16* __restrict__ x16) {
  int i = (blockIdx.x * 256 + threadIdx.x) * 4;
  float4 v = *(const float4*)(x + i);
  f16x4 o = { (f16)v.x, (f16)v.y, (f16)v.z, (f16)v.w };
  *(f16x4*)(x16 + i) = o;
}

// ------------- fp32 -> fp16 convert + transpose of W -------------
// Wt[widx][n][k] = W[k][n]; W_q additionally scaled by 1/sqrt(units).
__global__ __launch_bounds__(256) void cvt_w_kernel(const float* __restrict__ Wq,
                                                    const float* __restrict__ Wk,
                                                    const float* __restrict__ Wv,
                                                    f16* __restrict__ Wt) {
  const float* W = blockIdx.y == 0 ? Wq : (blockIdx.y == 1 ? Wk : Wv);
  const float s = blockIdx.y == 0 ? SCALE : 1.0f;
  f16* o = Wt + (size_t)blockIdx.y * DN * UN;
  int t = blockIdx.x * 256 + threadIdx.x;   // 0..65535
  int r  = t >> 7;          // k row 0..511
  int c4 = (t & 127) * 4;   // n col
  float4 v = *(const float4*)(W + (size_t)r * UN + c4);
  o[(size_t)(c4 + 0) * DN + r] = (f16)(v.x * s);
  o[(size_t)(c4 + 1) * DN + r] = (f16)(v.y * s);
  o[(size_t)(c4 + 2) * DN + r] = (f16)(v.z * s);
  o[(size_t)(c4 + 3) * DN + r] = (f16)(v.w * s);
}

// ---------------- QKV projection GEMM (unchanged) ----------------
__global__ __launch_bounds__(256) void qkv_gemm(const f16* __restrict__ x16,
                                                const f16* __restrict__ Wt,
                                                f16* __restrict__ Qh,
                                                f16* __restrict__ Kh,
                                                f16* __restrict__ Vt) {
  __shared__ __align__(16) f16 As[128 * 32];
  __shared__ __align__(16) f16 Bs[128 * 32];

  const int tid = threadIdx.x;
  const int w = tid >> 6, lane = tid & 63;
  const int l15 = lane & 15, lh = lane >> 4;
  const int m0 = blockIdx.x * 128;
  const int n0 = blockIdx.y * 128;
  const int widx = blockIdx.z;
  const f16* Wbase = Wt + (size_t)widx * DN * UN;

  const int wr = (w >> 1) * 64, wc = (w & 1) * 64;
  f32x4 acc[4][4] = {};

  for (int kk = 0; kk < 16; ++kk) {
    const int k0 = kk * 32;
#pragma unroll
    for (int q = 0; q < 2; ++q) {
      int j = q * 256 + tid;           // LDS 16B-chunk index
      int r = j >> 2, cs = j & 3;
      int c = cs ^ ((r >> 1) & 3);     // inverse swizzle on the SOURCE
      f16* abase = &As[(q * 256 + w * 64) * 8];
      f16* bbase = &Bs[(q * 256 + w * 64) * 8];
      gload_lds16(x16 + (size_t)(m0 + r) * DN + k0 + c * 8, abase);
      gload_lds16(Wbase + (size_t)(n0 + r) * DN + k0 + c * 8, bbase);
    }
    __syncthreads();

    f16x8 a[4], bfr[4];
#pragma unroll
    for (int m = 0; m < 4; ++m) {
      int row = wr + m * 16 + l15;
      int ch = lh ^ ((row >> 1) & 3);
      a[m] = *(const f16x8*)&As[row * 32 + ch * 8];
    }
#pragma unroll
    for (int n = 0; n < 4; ++n) {
      int row = wc + n * 16 + l15;
      int ch = lh ^ ((row >> 1) & 3);
      bfr[n] = *(const f16x8*)&Bs[row * 32 + ch * 8];
    }
#pragma unroll
    for (int m = 0; m < 4; ++m)
#pragma unroll
      for (int n = 0; n < 4; ++n)
        acc[m][n] = __builtin_amdgcn_mfma_f32_16x16x32_f16(a[m], bfr[n], acc[m][n], 0, 0, 0);
    __syncthreads();
  }

  if (widx == 2) {
#pragma unroll
    for (int m = 0; m < 4; ++m) {
      int g = m0 + wr + m * 16 + lh * 4;
      int bb = g >> 11;
      int ss = g & 2047;
#pragma unroll
      for (int n = 0; n < 4; ++n) {
        int u = n0 + wc + n * 16 + l15;
        f16x4 pv = { (f16)acc[m][n][0], (f16)acc[m][n][1],
                     (f16)acc[m][n][2], (f16)acc[m][n][3] };
        *(f16x4*)(Vt + ((size_t)bb * UN + u) * SN + ss) = pv;  // V^T[b][u][s]
      }
    }
  } else {
    f16* O = (widx == 0) ? Qh : Kh;
#pragma unroll
    for (int m = 0; m < 4; ++m)
#pragma unroll
      for (int n = 0; n < 4; ++n)
#pragma unroll
        for (int j = 0; j < 4; ++j)
          O[(size_t)(m0 + wr + m * 16 + lh * 4 + j) * UN + (n0 + wc + n * 16 + l15)] =
              (f16)acc[m][n][j];
  }
}

// ---------------- fused flash attention v3 ----------------
// QBLK=32 -> grid 512 blocks (2 blocks/CU), 512 threads = 8 waves,
// VGPR<=128 (launch_bounds 4 waves/EU) -> 16 waves/CU.
// Wave (rb = w>>2 in {0,1}: 16 q-rows; cq = w&3: kv-quarter for QK, u-quarter for PV).
// K tile 64x512 single-buffered; staging of tile t+1 issued right after the
// QK-read barrier so it overlaps softmax+PV. V^T frags direct from global (L2).
__global__ __launch_bounds__(512, 4) void attn_kernel(const f16* __restrict__ Qh,
                                                      const f16* __restrict__ Kh,
                                                      const f16* __restrict__ Vt,
                                                      float* __restrict__ out) {
  __shared__ __align__(16) f16 Ks[64 * 512];   // 64 KB, chunk-swizzled
  __shared__ __align__(16) f16 Ps[32 * 72];    // 4.5 KB
  __shared__ float redm[4][2][16];             // [cq][rb][row]
  __shared__ float redl[4][2][16];

  const int tid = threadIdx.x;
  const int w = tid >> 6, lane = tid & 63;
  const int l15 = lane & 15, lh = lane >> 4;
  const int bid = blockIdx.x;
  const int b = bid & 7;              // XCD pin: batch per XCD (K+V = 4MB = L2)
  const int q0 = (bid >> 3) * 32;
  const int rb = w >> 2;              // q-group (16 rows)
  const int cq = w & 3;               // kv-quarter (QK) / u-quarter (PV)

  const f16* Kbat = Kh + (size_t)b * SN * DN;
  const f16* Vbat = Vt + (size_t)b * UN * SN;

  // Q A-frags: row = l15 -> q0+rb*16+l15, k = kc*32 + lh*8
  const f16* Qbase = Qh + (size_t)(b * SN + q0 + rb * 16 + l15) * DN;
  f16x8 qf[16];
#pragma unroll
  for (int kc = 0; kc < 16; ++kc)
    qf[kc] = *(const f16x8*)(Qbase + kc * 32 + lh * 8);

  f32x4 acc[8] = {};                  // O[q=rb*16+lh*4+j][u=cq*128+n*16+l15]
  float mj[4] = { -1e30f, -1e30f, -1e30f, -1e30f };
  float lj[4] = { 0.f, 0.f, 0.f, 0.f };

  // prologue: stage tile 0
#pragma unroll
  for (int q = 0; q < 8; ++q) {
    int r = w * 8 + q;
    gload_lds16(Kbat + (size_t)r * DN + (lane ^ (r & 7)) * 8, &Ks[r * 512]);
  }
  __syncthreads();

  const int swz = l15 & 7;            // K-row swizzle key (row = cq*16+l15)

  for (int t = 0; t < 32; ++t) {
    const int kv0 = t * 64;

    // ---- QK^T: S[q=rb*16+lh*4+j][kv=cq*16+l15], k=512
    f32x4 sc = {};
    const int krow = cq * 16 + l15;
    __builtin_amdgcn_s_setprio(1);
#pragma unroll
    for (int kc = 0; kc < 16; ++kc) {
      f16x8 kf = *(const f16x8*)&Ks[krow * 512 + (((kc * 4 + lh) ^ swz) * 8)];
      sc = __builtin_amdgcn_mfma_f32_16x16x32_f16(qf[kc], kf, sc, 0, 0, 0);
    }
    __builtin_amdgcn_s_setprio(0);

    // intra-wave row max over this wave's 16 kv (reduce across l15)
    float tmax[4];
#pragma unroll
    for (int j = 0; j < 4; ++j) tmax[j] = sc[j];
#pragma unroll
    for (int off = 1; off < 16; off <<= 1)
#pragma unroll
      for (int j = 0; j < 4; ++j)
        tmax[j] = fmaxf(tmax[j], __shfl_xor(tmax[j], off, 64));
    if (l15 == 0) {
#pragma unroll
      for (int j = 0; j < 4; ++j) redm[cq][rb][lh * 4 + j] = tmax[j];
    }
    __syncthreads();   // b1: QK reads of Ks done + redm visible

    // issue staging of tile t+1 (overlaps softmax + PV)
    if (t < 31) {
#pragma unroll
      for (int q = 0; q < 8; ++q) {
        int r = w * 8 + q;
        gload_lds16(Kbat + (size_t)(kv0 + 64 + r) * DN + (lane ^ (r & 7)) * 8,
                    &Ks[r * 512]);
      }
    }

    // combine maxes across the 4 kv-quarters; defer-max rescale (T13)
    float mnew[4];
#pragma unroll
    for (int j = 0; j < 4; ++j) {
      float m01 = fmaxf(redm[0][rb][lh * 4 + j], redm[1][rb][lh * 4 + j]);
      float m23 = fmaxf(redm[2][rb][lh * 4 + j], redm[3][rb][lh * 4 + j]);
      mnew[j] = fmaxf(fmaxf(m01, m23), mj[j]);
    }
    bool need = !(mnew[0] <= mj[0] + DEFER_THR && mnew[1] <= mj[1] + DEFER_THR &&
                  mnew[2] <= mj[2] + DEFER_THR && mnew[3] <= mj[3] + DEFER_THR);
    if (__any(need)) {
#pragma unroll
      for (int j = 0; j < 4; ++j) {
        float rs = exp2f((mj[j] - mnew[j]) * LOG2E);
        mj[j] = mnew[j];
        lj[j] *= rs;
#pragma unroll
        for (int n = 0; n < 8; ++n) acc[n][j] *= rs;
      }
    }

    // P = exp(s - m): write to Ps, accumulate row sums
    float tsum[4];
#pragma unroll
    for (int j = 0; j < 4; ++j) {
      float p = exp2f((sc[j] - mj[j]) * LOG2E);
      tsum[j] = p;
      Ps[(rb * 16 + lh * 4 + j) * 72 + cq * 16 + l15] = (f16)p;
    }
#pragma unroll
    for (int off = 1; off < 16; off <<= 1)
#pragma unroll
      for (int j = 0; j < 4; ++j) tsum[j] += __shfl_xor(tsum[j], off, 64);
    if (l15 == 0) {
#pragma unroll
      for (int j = 0; j < 4; ++j) redl[cq][rb][lh * 4 + j] = tsum[j];
    }
    __syncthreads();   // b2: Ps + redl visible
#pragma unroll
    for (int j = 0; j < 4; ++j)
      lj[j] += (redl[0][rb][lh * 4 + j] + redl[1][rb][lh * 4 + j]) +
               (redl[2][rb][lh * 4 + j] + redl[3][rb][lh * 4 + j]);

    // ---- PV: O[16q][u-quarter 128] += P[16q][64kv] * V[64kv][128u]
    f16x8 pa0 = *(const f16x8*)&Ps[(rb * 16 + l15) * 72 + lh * 8];
    f16x8 pa1 = *(const f16x8*)&Ps[(rb * 16 + l15) * 72 + 32 + lh * 8];
    const f16* vb = Vbat + (size_t)(cq * 128 + l15) * SN + kv0 + lh * 8;
    __builtin_amdgcn_s_setprio(1);
#pragma unroll
    for (int n = 0; n < 8; ++n) {
      f16x8 v0 = *(const f16x8*)(vb + (size_t)(n * 16) * SN);
      f16x8 v1 = *(const f16x8*)(vb + (size_t)(n * 16) * SN + 32);
      acc[n] = __builtin_amdgcn_mfma_f32_16x16x32_f16(pa0, v0, acc[n], 0, 0, 0);
      acc[n] = __builtin_amdgcn_mfma_f32_16x16x32_f16(pa1, v1, acc[n], 0, 0, 0);
    }
    __builtin_amdgcn_s_setprio(0);

    __syncthreads();   // b3: staging done (vmcnt drain) + Ps reads retired
  }

  // epilogue: normalize + write fp32 output
  float inv[4];
#pragma unroll
  for (int j = 0; j < 4; ++j) inv[j] = 1.0f / lj[j];
#pragma unroll
  for (int j = 0; j < 4; ++j) {
    float* orow = out + (size_t)(b * SN + q0 + rb * 16 + lh * 4 + j) * UN +
                  cq * 128 + l15;
#pragma unroll
    for (int n = 0; n < 8; ++n) orow[n * 16] = acc[n][j] * inv[j];
  }
}

extern "C" void kernel_launch(void* const* d_in, const int* in_sizes, int n_in,
                              void* d_out, int out_size, void* d_ws, size_t ws_size,
                              hipStream_t stream) {
  const float* x  = (const float*)d_in[0];
  const float* Wq = (const float*)d_in[1];
  const float* Wk = (const float*)d_in[2];
  const float* Wv = (const float*)d_in[3];
  float* out = (float*)d_out;

  f16* x16 = (f16*)d_ws;
  f16* Wt  = x16 + (size_t)MN * DN;
  f16* Qh  = Wt + (size_t)3 * DN * UN;
  f16* Kh  = Qh + (size_t)MN * UN;
  f16* Vt  = Kh + (size_t)MN * UN;

  cvt_x_kernel<<<dim3(MN * DN / 1024), 256, 0, stream>>>(x, x16);
  cvt_w_kernel<<<dim3(256, 3), 256, 0, stream>>>(Wq, Wk, Wv, Wt);
  qkv_gemm<<<dim3(128, 4, 3), 256, 0, stream>>>(x16, Wt, Qh, Kh, Vt);
  attn_kernel<<<dim3(512), 512, 0, stream>>>(Qh, Kh, Vt, out);
}

// Round 6
// 282.565 us; speedup vs baseline: 1.9365x; 1.9365x over previous
//
#include <hip/hip_runtime.h>
#include <math.h>

#define BN 8
#define SN 2048
#define DN 512
#define UN 512
#define MN (BN*SN)   // 16384

typedef _Float16 f16;
typedef _Float16 f16x8 __attribute__((ext_vector_type(8)));
typedef _Float16 f16x4 __attribute__((ext_vector_type(4)));
typedef _Float16 f16x2 __attribute__((ext_vector_type(2)));
typedef float    f32x4 __attribute__((ext_vector_type(4)));

#define SCALE 0.044194173824159216f   // 1/sqrt(512), folded into W_q at convert
#define LOG2E 1.4426950408889634f

#define CVT_PK(a, b) __builtin_bit_cast(f16x2, __builtin_amdgcn_cvt_pkrtz((a), (b)))

__device__ __forceinline__ void gload_lds16(const f16* g, f16* l) {
  __builtin_amdgcn_global_load_lds(
      (const __attribute__((address_space(1))) unsigned int*)g,
      (__attribute__((address_space(3))) unsigned int*)l, 16, 0, 0);
}

// ---------------- fp32 -> fp16 convert of x ----------------
__global__ __launch_bounds__(256) void cvt_x_kernel(const float* __restrict__ x,
                                                    f16* __restrict__ x16) {
  int i = (blockIdx.x * 256 + threadIdx.x) * 4;
  float4 v = *(const float4*)(x + i);
  f16x4 o = { (f16)v.x, (f16)v.y, (f16)v.z, (f16)v.w };
  *(f16x4*)(x16 + i) = o;
}

// ------------- fp32 -> fp16 convert + transpose of W -------------
// Wt[widx][n][k] = W[k][n]; W_q additionally scaled by 1/sqrt(units).
__global__ __launch_bounds__(256) void cvt_w_kernel(const float* __restrict__ Wq,
                                                    const float* __restrict__ Wk,
                                                    const float* __restrict__ Wv,
                                                    f16* __restrict__ Wt) {
  const float* W = blockIdx.y == 0 ? Wq : (blockIdx.y == 1 ? Wk : Wv);
  const float s = blockIdx.y == 0 ? SCALE : 1.0f;
  f16* o = Wt + (size_t)blockIdx.y * DN * UN;
  int t = blockIdx.x * 256 + threadIdx.x;   // 0..65535
  int r  = t >> 7;          // k row 0..511
  int c4 = (t & 127) * 4;   // n col
  float4 v = *(const float4*)(W + (size_t)r * UN + c4);
  o[(size_t)(c4 + 0) * DN + r] = (f16)(v.x * s);
  o[(size_t)(c4 + 1) * DN + r] = (f16)(v.y * s);
  o[(size_t)(c4 + 2) * DN + r] = (f16)(v.z * s);
  o[(size_t)(c4 + 3) * DN + r] = (f16)(v.w * s);
}

// ---------------- QKV projection GEMM (unchanged) ----------------
__global__ __launch_bounds__(256) void qkv_gemm(const f16* __restrict__ x16,
                                                const f16* __restrict__ Wt,
                                                f16* __restrict__ Qh,
                                                f16* __restrict__ Kh,
                                                f16* __restrict__ Vt) {
  __shared__ __align__(16) f16 As[128 * 32];
  __shared__ __align__(16) f16 Bs[128 * 32];

  const int tid = threadIdx.x;
  const int w = tid >> 6, lane = tid & 63;
  const int l15 = lane & 15, lh = lane >> 4;
  const int m0 = blockIdx.x * 128;
  const int n0 = blockIdx.y * 128;
  const int widx = blockIdx.z;
  const f16* Wbase = Wt + (size_t)widx * DN * UN;

  const int wr = (w >> 1) * 64, wc = (w & 1) * 64;
  f32x4 acc[4][4] = {};

  for (int kk = 0; kk < 16; ++kk) {
    const int k0 = kk * 32;
#pragma unroll
    for (int q = 0; q < 2; ++q) {
      int j = q * 256 + tid;           // LDS 16B-chunk index
      int r = j >> 2, cs = j & 3;
      int c = cs ^ ((r >> 1) & 3);     // inverse swizzle on the SOURCE
      f16* abase = &As[(q * 256 + w * 64) * 8];
      f16* bbase = &Bs[(q * 256 + w * 64) * 8];
      gload_lds16(x16 + (size_t)(m0 + r) * DN + k0 + c * 8, abase);
      gload_lds16(Wbase + (size_t)(n0 + r) * DN + k0 + c * 8, bbase);
    }
    __syncthreads();

    f16x8 a[4], bfr[4];
#pragma unroll
    for (int m = 0; m < 4; ++m) {
      int row = wr + m * 16 + l15;
      int ch = lh ^ ((row >> 1) & 3);
      a[m] = *(const f16x8*)&As[row * 32 + ch * 8];
    }
#pragma unroll
    for (int n = 0; n < 4; ++n) {
      int row = wc + n * 16 + l15;
      int ch = lh ^ ((row >> 1) & 3);
      bfr[n] = *(const f16x8*)&Bs[row * 32 + ch * 8];
    }
#pragma unroll
    for (int m = 0; m < 4; ++m)
#pragma unroll
      for (int n = 0; n < 4; ++n)
        acc[m][n] = __builtin_amdgcn_mfma_f32_16x16x32_f16(a[m], bfr[n], acc[m][n], 0, 0, 0);
    __syncthreads();
  }

  if (widx == 2) {
#pragma unroll
    for (int m = 0; m < 4; ++m) {
      int g = m0 + wr + m * 16 + lh * 4;
      int bb = g >> 11;
      int ss = g & 2047;
#pragma unroll
      for (int n = 0; n < 4; ++n) {
        int u = n0 + wc + n * 16 + l15;
        f16x4 pv = { (f16)acc[m][n][0], (f16)acc[m][n][1],
                     (f16)acc[m][n][2], (f16)acc[m][n][3] };
        *(f16x4*)(Vt + ((size_t)bb * UN + u) * SN + ss) = pv;  // V^T[b][u][s]
      }
    }
  } else {
    f16* O = (widx == 0) ? Qh : Kh;
#pragma unroll
    for (int m = 0; m < 4; ++m)
#pragma unroll
      for (int n = 0; n < 4; ++n)
#pragma unroll
        for (int j = 0; j < 4; ++j)
          O[(size_t)(m0 + wr + m * 16 + lh * 4 + j) * UN + (n0 + wc + n * 16 + l15)] =
              (f16)acc[m][n][j];
  }
}

// ---------------- fused flash attention v5 ----------------
// QBLK=64, KVBLK=64, 256 blocks (1/CU, XCD-pinned batch), 512 thr = 8 waves.
// QK phase: wave (rb=w>>1 q-group, cs=w&1 kv-half), swapped mfma(K,Q_regs):
//   lane-local softmax rows (q = l15). P -> Ps (padded LDS).
// PV phase: wave = u-eighth (w*64), all 64 q: V B-frag reused 4x.
// K staged via global_load_lds (overlapped); V staged global->reg->LDS (T14).
__global__ __launch_bounds__(512, 2) void attn_kernel(const f16* __restrict__ Qh,
                                                      const f16* __restrict__ Kh,
                                                      const f16* __restrict__ Vt,
                                                      float* __restrict__ out) {
  __shared__ __align__(16) f16 Ks[64 * 512];   // 64 KB [kv][k], chunk-swz c^(r&7)
  __shared__ __align__(16) f16 Vs[512 * 64];   // 64 KB [u][kv], chunk-swz c^(u&7)
  __shared__ __align__(16) f16 Ps[64 * 72];    // 9 KB  [q][kv+pad]
  __shared__ float redm[2][4][16];             // [cs][rb][q]
  __shared__ float redl[2][4][16];

  const int tid = threadIdx.x;
  const int w = tid >> 6, lane = tid & 63;
  const int l15 = lane & 15, lh = lane >> 4;
  const int bid = blockIdx.x;
  const int b = bid & 7;              // XCD pin: batch per XCD (K+V = 4MB = L2)
  const int q0 = (bid >> 3) * 64;
  const int rb = w >> 1;              // QK q-group (16 rows)
  const int cs = w & 1;               // QK kv-half (32 cols)

  const f16* Kbat = Kh + (size_t)b * SN * DN;
  const f16* Vbat = Vt + (size_t)b * UN * SN;

  // Q B-frags: col q = q0+rb*16+l15, k = kc*32+lh*8
  const f16* Qbase = Qh + (size_t)(b * SN + q0 + rb * 16 + l15) * DN;
  f16x8 qf[16];
#pragma unroll
  for (int kc = 0; kc < 16; ++kc)
    qf[kc] = *(const f16x8*)(Qbase + kc * 32 + lh * 8);

  f32x4 acc[4][4] = {};               // [ut][qt]: O[q=qt*16+lh*4+j][u=w*64+ut*16+l15]
  f32x4 mj[4];
#pragma unroll
  for (int qt = 0; qt < 4; ++qt) mj[qt] = { -1e30f, -1e30f, -1e30f, -1e30f };
  float mrow = -1e30f, lrow = 0.f;

  // V row owned by this thread (512 threads = 512 u-rows)
  const f16* vsrc = Vbat + (size_t)tid * SN;
  f16* vdst = &Vs[tid * 64];
  const int vswz = tid & 7;

  // ---- prologue: K(0) DMA + V(0) via regs
#pragma unroll
  for (int q = 0; q < 8; ++q) {
    int r = w * 8 + q;
    gload_lds16(Kbat + (size_t)r * DN + (lane ^ (r & 7)) * 8, &Ks[r * 512]);
  }
  f16x8 vreg[8];
#pragma unroll
  for (int j = 0; j < 8; ++j) vreg[j] = *(const f16x8*)(vsrc + j * 8);
  __syncthreads();                    // K(0) drained
#pragma unroll
  for (int j = 0; j < 8; ++j)
    *(f16x8*)(vdst + (j ^ vswz) * 8) = vreg[j];
  __syncthreads();                    // V(0) visible

  const int kswz = l15 & 7;

  for (int t = 0; t < 32; ++t) {
    const int kv0 = t * 64;

    // issue V(t+1) global->reg prefetch (hidden under QK+softmax+PV)
    if (t < 31) {
#pragma unroll
      for (int j = 0; j < 8; ++j)
        vreg[j] = *(const f16x8*)(vsrc + kv0 + 64 + j * 8);
    }

    // ---- QK^T swapped: sc C-layout col=l15=q, row=lh*4+j=kv
    f32x4 sc0 = {}, sc1 = {};
    const int r0 = cs * 32 + l15;
#pragma unroll
    for (int kc = 0; kc < 16; ++kc) {
      int ch = ((kc * 4 + lh) ^ kswz) * 8;
      f16x8 k0 = *(const f16x8*)&Ks[r0 * 512 + ch];
      f16x8 k1 = *(const f16x8*)&Ks[(r0 + 16) * 512 + ch];
      sc0 = __builtin_amdgcn_mfma_f32_16x16x32_f16(k0, qf[kc], sc0, 0, 0, 0);
      sc1 = __builtin_amdgcn_mfma_f32_16x16x32_f16(k1, qf[kc], sc1, 0, 0, 0);
    }

    // per-row (q=l15) max over this wave's 32 kv
    float pm = fmaxf(fmaxf(fmaxf(sc0[0], sc0[1]), fmaxf(sc0[2], sc0[3])),
                     fmaxf(fmaxf(sc1[0], sc1[1]), fmaxf(sc1[2], sc1[3])));
    pm = fmaxf(pm, __shfl_xor(pm, 16, 64));
    pm = fmaxf(pm, __shfl_xor(pm, 32, 64));
    if (lh == 0) redm[cs][rb][l15] = pm;
    __syncthreads();                  // bar1: Ks reads done + redm ready

    // issue K(t+1) DMA into Ks (no readers until bar4)
    if (t < 31) {
#pragma unroll
      for (int q = 0; q < 8; ++q) {
        int r = w * 8 + q;
        gload_lds16(Kbat + (size_t)(kv0 + 64 + r) * DN + (lane ^ (r & 7)) * 8,
                    &Ks[r * 512]);
      }
    }

    // PV-layout running max + acc rescale (rows q = qt*16+lh*4+j)
#pragma unroll
    for (int qt = 0; qt < 4; ++qt) {
      f32x4 m0 = *(const f32x4*)&redm[0][qt][lh * 4];
      f32x4 m1 = *(const f32x4*)&redm[1][qt][lh * 4];
      f32x4 rs;
#pragma unroll
      for (int j = 0; j < 4; ++j) {
        float mn = fmaxf(mj[qt][j], fmaxf(m0[j], m1[j]));
        rs[j] = exp2f((mj[qt][j] - mn) * LOG2E);
        mj[qt][j] = mn;
      }
#pragma unroll
      for (int ut = 0; ut < 4; ++ut) {
        acc[ut][qt][0] *= rs[0]; acc[ut][qt][1] *= rs[1];
        acc[ut][qt][2] *= rs[2]; acc[ut][qt][3] *= rs[3];
      }
    }

    // QK-wave row scalar m + P + partial row sum
    float mnr = fmaxf(mrow, fmaxf(redm[0][rb][l15], redm[1][rb][l15]));
    float rsr = exp2f((mrow - mnr) * LOG2E);
    mrow = mnr;
    float p[8];
#pragma unroll
    for (int j = 0; j < 4; ++j) {
      p[j]     = exp2f((sc0[j] - mrow) * LOG2E);
      p[4 + j] = exp2f((sc1[j] - mrow) * LOG2E);
    }
    float ts = (p[0] + p[1]) + (p[2] + p[3]) + (p[4] + p[5]) + (p[6] + p[7]);
    ts += __shfl_xor(ts, 16, 64);
    ts += __shfl_xor(ts, 32, 64);
    lrow = lrow * rsr + ts;

    const int pbase = (rb * 16 + l15) * 72 + cs * 32 + lh * 4;
    *(f16x2*)&Ps[pbase +  0] = CVT_PK(p[0], p[1]);
    *(f16x2*)&Ps[pbase +  2] = CVT_PK(p[2], p[3]);
    *(f16x2*)&Ps[pbase + 16] = CVT_PK(p[4], p[5]);
    *(f16x2*)&Ps[pbase + 18] = CVT_PK(p[6], p[7]);
    __syncthreads();                  // bar2: Ps ready

    // ---- PV: wave = u-eighth (w*64), all 64 q; V B-frag reused 4x
#pragma unroll
    for (int ks = 0; ks < 2; ++ks) {
      f16x8 pf[4];
#pragma unroll
      for (int qt = 0; qt < 4; ++qt)
        pf[qt] = *(const f16x8*)&Ps[(qt * 16 + l15) * 72 + ks * 32 + lh * 8];
#pragma unroll
      for (int ut = 0; ut < 4; ++ut) {
        int ur = w * 64 + ut * 16 + l15;
        f16x8 vf = *(const f16x8*)&Vs[ur * 64 + (((ks * 4 + lh) ^ (l15 & 7)) * 8)];
#pragma unroll
        for (int qt = 0; qt < 4; ++qt)
          acc[ut][qt] = __builtin_amdgcn_mfma_f32_16x16x32_f16(pf[qt], vf, acc[ut][qt], 0, 0, 0);
      }
    }
    __syncthreads();                  // bar3: Vs reads done

    if (t < 31) {
#pragma unroll
      for (int j = 0; j < 8; ++j)
        *(f16x8*)(vdst + (j ^ vswz) * 8) = vreg[j];
    }
    __syncthreads();                  // bar4: V(t+1) visible + K DMA drained
  }

  // ---- epilogue
  if (lh == 0) redl[cs][rb][l15] = lrow;
  __syncthreads();
  f32x4 linv[4];
#pragma unroll
  for (int qt = 0; qt < 4; ++qt) {
    f32x4 l0 = *(const f32x4*)&redl[0][qt][lh * 4];
    f32x4 l1 = *(const f32x4*)&redl[1][qt][lh * 4];
#pragma unroll
    for (int j = 0; j < 4; ++j) linv[qt][j] = 1.0f / (l0[j] + l1[j]);
  }
#pragma unroll
  for (int qt = 0; qt < 4; ++qt)
#pragma unroll
    for (int j = 0; j < 4; ++j) {
      float* orow = out + (size_t)(b * SN + q0 + qt * 16 + lh * 4 + j) * UN + w * 64 + l15;
#pragma unroll
      for (int ut = 0; ut < 4; ++ut)
        orow[ut * 16] = acc[ut][qt][j] * linv[qt][j];
    }
}

extern "C" void kernel_launch(void* const* d_in, const int* in_sizes, int n_in,
                              void* d_out, int out_size, void* d_ws, size_t ws_size,
                              hipStream_t stream) {
  const float* x  = (const float*)d_in[0];
  const float* Wq = (const float*)d_in[1];
  const float* Wk = (const float*)d_in[2];
  const float* Wv = (const float*)d_in[3];
  float* out = (float*)d_out;

  f16* x16 = (f16*)d_ws;
  f16* Wt  = x16 + (size_t)MN * DN;
  f16* Qh  = Wt + (size_t)3 * DN * UN;
  f16* Kh  = Qh + (size_t)MN * UN;
  f16* Vt  = Kh + (size_t)MN * UN;

  cvt_x_kernel<<<dim3(MN * DN / 1024), 256, 0, stream>>>(x, x16);
  cvt_w_kernel<<<dim3(256, 3), 256, 0, stream>>>(Wq, Wk, Wv, Wt);
  qkv_gemm<<<dim3(128, 4, 3), 256, 0, stream>>>(x16, Wt, Qh, Kh, Vt);
  attn_kernel<<<256, 512, 0, stream>>>(Qh, Kh, Vt, out);
}

// Round 7
// 260.723 us; speedup vs baseline: 2.0987x; 1.0838x over previous
//
#include <hip/hip_runtime.h>
#include <math.h>

#define BN 8
#define SN 2048
#define DN 512
#define UN 512
#define MN (BN*SN)   // 16384

typedef _Float16 f16;
typedef _Float16 f16x8 __attribute__((ext_vector_type(8)));
typedef _Float16 f16x4 __attribute__((ext_vector_type(4)));
typedef _Float16 f16x2 __attribute__((ext_vector_type(2)));
typedef float    f32x4 __attribute__((ext_vector_type(4)));

#define SCALE 0.044194173824159216f   // 1/sqrt(512), folded into W_q at convert
#define LOG2E 1.4426950408889634f

#define CVT_PK(a, b) __builtin_bit_cast(f16x2, __builtin_amdgcn_cvt_pkrtz((a), (b)))

// raw barrier + explicit producer-side waits (T3/T4-lite):
// lgkm-only barriers let global loads stay in flight across them.
#define BAR_LGKM() do {                                         \
  asm volatile("s_waitcnt lgkmcnt(0)" ::: "memory");            \
  __builtin_amdgcn_s_barrier();                                 \
  __builtin_amdgcn_sched_barrier(0);                            \
} while (0)
#define BAR_FULL() do {                                         \
  asm volatile("s_waitcnt vmcnt(0) lgkmcnt(0)" ::: "memory");   \
  __builtin_amdgcn_s_barrier();                                 \
  __builtin_amdgcn_sched_barrier(0);                            \
} while (0)

__device__ __forceinline__ void gload_lds16(const f16* g, f16* l) {
  __builtin_amdgcn_global_load_lds(
      (const __attribute__((address_space(1))) unsigned int*)g,
      (__attribute__((address_space(3))) unsigned int*)l, 16, 0, 0);
}

// ---------------- fp32 -> fp16 convert of x ----------------
__global__ __launch_bounds__(256) void cvt_x_kernel(const float* __restrict__ x,
                                                    f16* __restrict__ x16) {
  int i = (blockIdx.x * 256 + threadIdx.x) * 4;
  float4 v = *(const float4*)(x + i);
  f16x4 o = { (f16)v.x, (f16)v.y, (f16)v.z, (f16)v.w };
  *(f16x4*)(x16 + i) = o;
}

// ------------- fp32 -> fp16 convert + transpose of W -------------
// Wt[widx][n][k] = W[k][n]; W_q additionally scaled by 1/sqrt(units).
__global__ __launch_bounds__(256) void cvt_w_kernel(const float* __restrict__ Wq,
                                                    const float* __restrict__ Wk,
                                                    const float* __restrict__ Wv,
                                                    f16* __restrict__ Wt) {
  const float* W = blockIdx.y == 0 ? Wq : (blockIdx.y == 1 ? Wk : Wv);
  const float s = blockIdx.y == 0 ? SCALE : 1.0f;
  f16* o = Wt + (size_t)blockIdx.y * DN * UN;
  int t = blockIdx.x * 256 + threadIdx.x;   // 0..65535
  int r  = t >> 7;          // k row 0..511
  int c4 = (t & 127) * 4;   // n col
  float4 v = *(const float4*)(W + (size_t)r * UN + c4);
  o[(size_t)(c4 + 0) * DN + r] = (f16)(v.x * s);
  o[(size_t)(c4 + 1) * DN + r] = (f16)(v.y * s);
  o[(size_t)(c4 + 2) * DN + r] = (f16)(v.z * s);
  o[(size_t)(c4 + 3) * DN + r] = (f16)(v.w * s);
}

// ---------------- QKV projection GEMM (unchanged) ----------------
__global__ __launch_bounds__(256) void qkv_gemm(const f16* __restrict__ x16,
                                                const f16* __restrict__ Wt,
                                                f16* __restrict__ Qh,
                                                f16* __restrict__ Kh,
                                                f16* __restrict__ Vt) {
  __shared__ __align__(16) f16 As[128 * 32];
  __shared__ __align__(16) f16 Bs[128 * 32];

  const int tid = threadIdx.x;
  const int w = tid >> 6, lane = tid & 63;
  const int l15 = lane & 15, lh = lane >> 4;
  const int m0 = blockIdx.x * 128;
  const int n0 = blockIdx.y * 128;
  const int widx = blockIdx.z;
  const f16* Wbase = Wt + (size_t)widx * DN * UN;

  const int wr = (w >> 1) * 64, wc = (w & 1) * 64;
  f32x4 acc[4][4] = {};

  for (int kk = 0; kk < 16; ++kk) {
    const int k0 = kk * 32;
#pragma unroll
    for (int q = 0; q < 2; ++q) {
      int j = q * 256 + tid;           // LDS 16B-chunk index
      int r = j >> 2, cs = j & 3;
      int c = cs ^ ((r >> 1) & 3);     // inverse swizzle on the SOURCE
      f16* abase = &As[(q * 256 + w * 64) * 8];
      f16* bbase = &Bs[(q * 256 + w * 64) * 8];
      gload_lds16(x16 + (size_t)(m0 + r) * DN + k0 + c * 8, abase);
      gload_lds16(Wbase + (size_t)(n0 + r) * DN + k0 + c * 8, bbase);
    }
    __syncthreads();

    f16x8 a[4], bfr[4];
#pragma unroll
    for (int m = 0; m < 4; ++m) {
      int row = wr + m * 16 + l15;
      int ch = lh ^ ((row >> 1) & 3);
      a[m] = *(const f16x8*)&As[row * 32 + ch * 8];
    }
#pragma unroll
    for (int n = 0; n < 4; ++n) {
      int row = wc + n * 16 + l15;
      int ch = lh ^ ((row >> 1) & 3);
      bfr[n] = *(const f16x8*)&Bs[row * 32 + ch * 8];
    }
#pragma unroll
    for (int m = 0; m < 4; ++m)
#pragma unroll
      for (int n = 0; n < 4; ++n)
        acc[m][n] = __builtin_amdgcn_mfma_f32_16x16x32_f16(a[m], bfr[n], acc[m][n], 0, 0, 0);
    __syncthreads();
  }

  if (widx == 2) {
#pragma unroll
    for (int m = 0; m < 4; ++m) {
      int g = m0 + wr + m * 16 + lh * 4;
      int bb = g >> 11;
      int ss = g & 2047;
#pragma unroll
      for (int n = 0; n < 4; ++n) {
        int u = n0 + wc + n * 16 + l15;
        f16x4 pv = { (f16)acc[m][n][0], (f16)acc[m][n][1],
                     (f16)acc[m][n][2], (f16)acc[m][n][3] };
        *(f16x4*)(Vt + ((size_t)bb * UN + u) * SN + ss) = pv;  // V^T[b][u][s]
      }
    }
  } else {
    f16* O = (widx == 0) ? Qh : Kh;
#pragma unroll
    for (int m = 0; m < 4; ++m)
#pragma unroll
      for (int n = 0; n < 4; ++n)
#pragma unroll
        for (int j = 0; j < 4; ++j)
          O[(size_t)(m0 + wr + m * 16 + lh * 4 + j) * UN + (n0 + wc + n * 16 + l15)] =
              (f16)acc[m][n][j];
  }
}

// ---------------- fused flash attention v6 ----------------
// v5 geometry (QBLK=64, KVBLK=64, 256 blocks, 8 waves) with fixed sync:
// 3 raw barriers/iter; lgkm-only at bar1/bar2 so the V-prefetch (global->reg)
// and K-DMA (global->LDS) stay in flight across them; single vmcnt(0) drain
// at bar3 whose cover is the whole iteration. Vs padded [512][72] (uniform
// 16B-slot banks, no XOR needed).
__global__ __launch_bounds__(512, 2) void attn_kernel(const f16* __restrict__ Qh,
                                                      const f16* __restrict__ Kh,
                                                      const f16* __restrict__ Vt,
                                                      float* __restrict__ out) {
  __shared__ __align__(16) f16 Ks[64 * 512];   // 64 KB [kv][k], chunk-swz c^(r&7)
  __shared__ __align__(16) f16 Vs[512 * 72];   // 72 KB [u][kv+pad8]
  __shared__ __align__(16) f16 Ps[64 * 72];    // 9 KB  [q][kv+pad8]
  __shared__ float redm[2][4][16];             // [cs][rb][q]
  __shared__ float redl[2][4][16];

  const int tid = threadIdx.x;
  const int w = tid >> 6, lane = tid & 63;
  const int l15 = lane & 15, lh = lane >> 4;
  const int bid = blockIdx.x;
  const int b = bid & 7;              // XCD pin: batch per XCD (K+V = 4MB = L2)
  const int q0 = (bid >> 3) * 64;
  const int rb = w >> 1;              // QK q-group (16 rows)
  const int cs = w & 1;               // QK kv-half (32 cols)

  const f16* Kbat = Kh + (size_t)b * SN * DN;
  const f16* Vbat = Vt + (size_t)b * UN * SN;

  // Q B-frags: col q = q0+rb*16+l15, k = kc*32+lh*8
  const f16* Qbase = Qh + (size_t)(b * SN + q0 + rb * 16 + l15) * DN;
  f16x8 qf[16];
#pragma unroll
  for (int kc = 0; kc < 16; ++kc)
    qf[kc] = *(const f16x8*)(Qbase + kc * 32 + lh * 8);

  f32x4 acc[4][4] = {};               // [ut][qt]: O[q=qt*16+lh*4+j][u=w*64+ut*16+l15]
  f32x4 mj[4];
#pragma unroll
  for (int qt = 0; qt < 4; ++qt) mj[qt] = { -1e30f, -1e30f, -1e30f, -1e30f };
  float mrow = -1e30f, lrow = 0.f;

  // V row owned by this thread (512 threads = 512 u-rows)
  const f16* vsrc = Vbat + (size_t)tid * SN;
  f16* vdst = &Vs[tid * 72];

  // ---- prologue: K(0) DMA + V(0) via regs
#pragma unroll
  for (int q = 0; q < 8; ++q) {
    int r = w * 8 + q;
    gload_lds16(Kbat + (size_t)r * DN + (lane ^ (r & 7)) * 8, &Ks[r * 512]);
  }
  f16x8 vreg[8];
#pragma unroll
  for (int j = 0; j < 8; ++j) vreg[j] = *(const f16x8*)(vsrc + j * 8);
  __syncthreads();                    // K(0) drained
#pragma unroll
  for (int j = 0; j < 8; ++j)
    *(f16x8*)(vdst + j * 8) = vreg[j];
  __syncthreads();                    // V(0) visible

  const int kswz = l15 & 7;

  for (int t = 0; t < 32; ++t) {
    const int kv0 = t * 64;

    // issue V(t+1) global->reg prefetch (drains only at bar3)
    if (t < 31) {
#pragma unroll
      for (int j = 0; j < 8; ++j)
        vreg[j] = *(const f16x8*)(vsrc + kv0 + 64 + j * 8);
    }

    // ---- QK^T swapped: sc C-layout col=l15=q, row=lh*4+j=kv
    f32x4 sc0 = {}, sc1 = {};
    const int r0 = cs * 32 + l15;
    __builtin_amdgcn_s_setprio(1);
#pragma unroll
    for (int kc = 0; kc < 16; ++kc) {
      int ch = ((kc * 4 + lh) ^ kswz) * 8;
      f16x8 k0 = *(const f16x8*)&Ks[r0 * 512 + ch];
      f16x8 k1 = *(const f16x8*)&Ks[(r0 + 16) * 512 + ch];
      sc0 = __builtin_amdgcn_mfma_f32_16x16x32_f16(k0, qf[kc], sc0, 0, 0, 0);
      sc1 = __builtin_amdgcn_mfma_f32_16x16x32_f16(k1, qf[kc], sc1, 0, 0, 0);
    }
    __builtin_amdgcn_s_setprio(0);

    // per-row (q=l15) max over this wave's 32 kv
    float pm = fmaxf(fmaxf(fmaxf(sc0[0], sc0[1]), fmaxf(sc0[2], sc0[3])),
                     fmaxf(fmaxf(sc1[0], sc1[1]), fmaxf(sc1[2], sc1[3])));
    pm = fmaxf(pm, __shfl_xor(pm, 16, 64));
    pm = fmaxf(pm, __shfl_xor(pm, 32, 64));
    if (lh == 0) redm[cs][rb][l15] = pm;
    BAR_LGKM();                       // bar1: Ks reads done + redm visible (vmem stays in flight)

    // issue K(t+1) DMA into Ks (readers all passed bar1; drains at bar3)
    if (t < 31) {
#pragma unroll
      for (int q = 0; q < 8; ++q) {
        int r = w * 8 + q;
        gload_lds16(Kbat + (size_t)(kv0 + 64 + r) * DN + (lane ^ (r & 7)) * 8,
                    &Ks[r * 512]);
      }
    }

    // PV-layout running max + acc rescale (rows q = qt*16+lh*4+j)
#pragma unroll
    for (int qt = 0; qt < 4; ++qt) {
      f32x4 m0 = *(const f32x4*)&redm[0][qt][lh * 4];
      f32x4 m1 = *(const f32x4*)&redm[1][qt][lh * 4];
      f32x4 rs;
#pragma unroll
      for (int j = 0; j < 4; ++j) {
        float mn = fmaxf(mj[qt][j], fmaxf(m0[j], m1[j]));
        rs[j] = exp2f((mj[qt][j] - mn) * LOG2E);
        mj[qt][j] = mn;
      }
#pragma unroll
      for (int ut = 0; ut < 4; ++ut) {
        acc[ut][qt][0] *= rs[0]; acc[ut][qt][1] *= rs[1];
        acc[ut][qt][2] *= rs[2]; acc[ut][qt][3] *= rs[3];
      }
    }

    // QK-wave row scalar m + P + partial row sum
    float mnr = fmaxf(mrow, fmaxf(redm[0][rb][l15], redm[1][rb][l15]));
    float rsr = exp2f((mrow - mnr) * LOG2E);
    mrow = mnr;
    float p[8];
#pragma unroll
    for (int j = 0; j < 4; ++j) {
      p[j]     = exp2f((sc0[j] - mrow) * LOG2E);
      p[4 + j] = exp2f((sc1[j] - mrow) * LOG2E);
    }
    float ts = (p[0] + p[1]) + (p[2] + p[3]) + (p[4] + p[5]) + (p[6] + p[7]);
    ts += __shfl_xor(ts, 16, 64);
    ts += __shfl_xor(ts, 32, 64);
    lrow = lrow * rsr + ts;

    const int pbase = (rb * 16 + l15) * 72 + cs * 32 + lh * 4;
    *(f16x2*)&Ps[pbase +  0] = CVT_PK(p[0], p[1]);
    *(f16x2*)&Ps[pbase +  2] = CVT_PK(p[2], p[3]);
    *(f16x2*)&Ps[pbase + 16] = CVT_PK(p[4], p[5]);
    *(f16x2*)&Ps[pbase + 18] = CVT_PK(p[6], p[7]);
    BAR_LGKM();                       // bar2: Ps visible (vmem still in flight)

    // ---- PV: wave = u-eighth (w*64), all 64 q; V B-frag reused 4x
    __builtin_amdgcn_s_setprio(1);
#pragma unroll
    for (int ks = 0; ks < 2; ++ks) {
      f16x8 pf[4];
#pragma unroll
      for (int qt = 0; qt < 4; ++qt)
        pf[qt] = *(const f16x8*)&Ps[(qt * 16 + l15) * 72 + ks * 32 + lh * 8];
#pragma unroll
      for (int ut = 0; ut < 4; ++ut) {
        int ur = w * 64 + ut * 16 + l15;
        f16x8 vf = *(const f16x8*)&Vs[ur * 72 + (ks * 4 + lh) * 8];
#pragma unroll
        for (int qt = 0; qt < 4; ++qt)
          acc[ut][qt] = __builtin_amdgcn_mfma_f32_16x16x32_f16(pf[qt], vf, acc[ut][qt], 0, 0, 0);
      }
    }
    __builtin_amdgcn_s_setprio(0);
    BAR_FULL();                       // bar3: PV reads done + K-DMA/V-pref drained
                                      // (cover = QK + softmax + PV of this iter)

    if (t < 31) {
#pragma unroll
      for (int j = 0; j < 8; ++j)
        *(f16x8*)(vdst + j * 8) = vreg[j];
      // V(t+1) writes become visible via lgkm drain at bar1(t+1) + bar2(t+1)
    }
  }

  // ---- epilogue
  if (lh == 0) redl[cs][rb][l15] = lrow;
  __syncthreads();
  f32x4 linv[4];
#pragma unroll
  for (int qt = 0; qt < 4; ++qt) {
    f32x4 l0 = *(const f32x4*)&redl[0][qt][lh * 4];
    f32x4 l1 = *(const f32x4*)&redl[1][qt][lh * 4];
#pragma unroll
    for (int j = 0; j < 4; ++j) linv[qt][j] = 1.0f / (l0[j] + l1[j]);
  }
#pragma unroll
  for (int qt = 0; qt < 4; ++qt)
#pragma unroll
    for (int j = 0; j < 4; ++j) {
      float* orow = out + (size_t)(b * SN + q0 + qt * 16 + lh * 4 + j) * UN + w * 64 + l15;
#pragma unroll
      for (int ut = 0; ut < 4; ++ut)
        orow[ut * 16] = acc[ut][qt][j] * linv[qt][j];
    }
}

extern "C" void kernel_launch(void* const* d_in, const int* in_sizes, int n_in,
                              void* d_out, int out_size, void* d_ws, size_t ws_size,
                              hipStream_t stream) {
  const float* x  = (const float*)d_in[0];
  const float* Wq = (const float*)d_in[1];
  const float* Wk = (const float*)d_in[2];
  const float* Wv = (const float*)d_in[3];
  float* out = (float*)d_out;

  f16* x16 = (f16*)d_ws;
  f16* Wt  = x16 + (size_t)MN * DN;
  f16* Qh  = Wt + (size_t)3 * DN * UN;
  f16* Kh  = Qh + (size_t)MN * UN;
  f16* Vt  = Kh + (size_t)MN * UN;

  cvt_x_kernel<<<dim3(MN * DN / 1024), 256, 0, stream>>>(x, x16);
  cvt_w_kernel<<<dim3(256, 3), 256, 0, stream>>>(Wq, Wk, Wv, Wt);
  qkv_gemm<<<dim3(128, 4, 3), 256, 0, stream>>>(x16, Wt, Qh, Kh, Vt);
  attn_kernel<<<256, 512, 0, stream>>>(Qh, Kh, Vt, out);
}